// Round 6
// baseline (113.654 us; speedup 1.0000x reference)
//
#include <hip/hip_runtime.h>
#include <hip/hip_cooperative_groups.h>
#include <math.h>

namespace cg = cooperative_groups;

#define BB 2
#define C_IN 32
#define HH 64
#define WW 64
#define J (HH*WW)        // 4096
#define HID 64
#define C_OUT 32
#define S 256
#define TN 128           // table knots per (b,h)
#define JT 32            // j's per eval block
#define GRID 256

// gelu(x) ~= x * sigmoid(A*x + B*x^3)  (tanh-form gelu, exp2 domain)
#define GELU_A 2.3022043f
#define GELU_B 0.10294306f

union SharedU {
    float us[4 * 66];               // phase 2: u[b,:,h] in 4 padded s-quarters
    struct {
        float Tl[HID][TN + 4];      // phase 3: row stride 132 floats (528 B, 16B-aligned)
        float G[JT][HID + 1];       // phase 3: gathered F values, padded
    } e;
};                                   // 42112 B static — under the 64 KB limit

// ---------- phase 1: u[b,s,hid] = b1 - sx*w0 - sy*w1 + vp[b,idx]@W1[2:] ----------
__device__ __forceinline__ void phase1(int blk, int tid,
    const float* __restrict__ v, const int* __restrict__ indices,
    const float* __restrict__ W1, const float* __restrict__ b1,
    float* __restrict__ u)
{
    if (blk >= BB * (S / 4)) return;     // 128 blocks, 4 s each
    int b   = blk >> 6;
    int s   = (blk & 63) * 4 + (tid >> 6);
    int hid = tid & 63;
    int idx = indices[s];
    float sx = (float)(idx & (WW - 1)) * (1.0f / (WW - 1));
    float sy = (float)(idx >> 6)       * (1.0f / (HH - 1));
    float acc = b1[hid] - sx * W1[hid] - sy * W1[HID + hid];
    const float* vb = v + (size_t)b * C_IN * J + idx;
    #pragma unroll
    for (int c = 0; c < C_IN; ++c) {
        acc += vb[c * J] * W1[(2 + c) * HID + hid];
    }
    u[((size_t)b * S + s) * HID + hid] = acc;
}

// ---------- phase 2: T[b,h,n] = sum_s gelu(c_n + u[b,s,h]) ----------
__device__ __forceinline__ void phase2(int blk, int tid, SharedU& sm,
    const float* __restrict__ u, const float* __restrict__ W1,
    float* __restrict__ T)
{
    int b     = blk >> 7;            // 0..1
    int q     = blk & 127;
    int h     = q >> 1;              // 0..63
    int halfk = q & 1;               // which 64 knots
    // padded quarters: us[(s>>6)*66 + (s&63)] -> conflict-free 4-addr reads
    sm.us[(tid >> 6) * 66 + (tid & 63)] = u[((size_t)b * S + tid) * HID + h];
    __syncthreads();

    float w0 = W1[h], w1 = W1[HID + h];
    float c0 = fminf(w0, 0.0f) + fminf(w1, 0.0f);
    float c1 = fmaxf(w0, 0.0f) + fmaxf(w1, 0.0f);
    float dc = fmaxf(c1 - c0, 1e-6f) * (1.0f / (TN - 1));
    int n  = halfk * 64 + (tid >> 2);    // knot index
    int sq = tid & 3;                    // s-quarter
    float cn = c0 + (float)n * dc;

    const float* usp = &sm.us[sq * 66];
    float acc = 0.0f;
    #pragma unroll 4
    for (int s = 0; s < 64; ++s) {
        float x = cn + usp[s];
        float p = __builtin_fmaf(-GELU_B, x * x, -GELU_A);
        float e = __builtin_amdgcn_exp2f(p * x);
        acc = __builtin_fmaf(x, __builtin_amdgcn_rcpf(e + 1.0f), acc);
    }
    acc += __shfl_xor(acc, 1);           // combine 4 s-quarters
    acc += __shfl_xor(acc, 2);
    if (sq == 0)
        T[((size_t)b * HID + h) * TN + n] = acc;
    __syncthreads();                     // us reads done before union reuse
}

// ---------- phase 3: interp + W2 epilogue ----------
__device__ __forceinline__ void phase3(int blk, int tid, SharedU& sm,
    const float* __restrict__ T, const float* __restrict__ W1,
    const float* __restrict__ W2, const float* __restrict__ b2,
    float* __restrict__ out)
{
    int b  = blk >> 7;
    int j0 = (blk & 127) * JT;

    // stage this batch's table (32 KB) into LDS, float4 loads
    const float4* Tb4 = (const float4*)(T + (size_t)b * HID * TN);
    #pragma unroll
    for (int k = tid; k < HID * TN / 4; k += 256) {   // 8 iters
        float4 vv = Tb4[k];
        int h = k >> 5;                  // 32 float4 per table row
        int n = (k & 31) * 4;
        *(float4*)&sm.e.Tl[h][n] = vv;   // row stride 528 B, 16B-aligned
    }
    __syncthreads();

    int jl = tid & 31;
    int j  = j0 + jl;
    float xj = (float)(j & (WW - 1)) * (1.0f / (WW - 1));
    float yj = (float)(j >> 6)       * (1.0f / (HH - 1));
    #pragma unroll
    for (int k = 0; k < 8; ++k) {
        int h = (tid >> 5) + k * 8;
        float w0 = W1[h], w1 = W1[HID + h];
        float c0 = fminf(w0, 0.0f) + fminf(w1, 0.0f);
        float c1 = fmaxf(w0, 0.0f) + fmaxf(w1, 0.0f);
        float inv = (float)(TN - 1) / fmaxf(c1 - c0, 1e-6f);
        float t  = (xj * w0 + yj * w1 - c0) * inv;
        int i = (int)t;
        i = max(0, min(TN - 2, i));
        float f = t - (float)i;
        float t0 = sm.e.Tl[h][i], t1 = sm.e.Tl[h][i + 1];
        sm.e.G[jl][h] = __builtin_fmaf(f, t1 - t0, t0);
    }
    __syncthreads();

    // out[b,co,j0+jj]: lanes vary jj -> coalesced stores, conflict-free G reads
    int jj = tid & 31;
    int cb = tid >> 5;                   // 0..7
    #pragma unroll
    for (int qq = 0; qq < 4; ++qq) {
        int co = cb + 8 * qq;
        float sum = 0.0f;
        #pragma unroll
        for (int h = 0; h < HID; ++h)
            sum = __builtin_fmaf(sm.e.G[jj][h], W2[h * C_OUT + co], sum);
        out[(size_t)b * C_OUT * J + (size_t)co * J + j0 + jj] = sum * (1.0f / S) + b2[co];
    }
}

// ---------- fused cooperative kernel ----------
__global__ __launch_bounds__(256) void nystrom_fused(
    const float* __restrict__ v, const int* __restrict__ indices,
    const float* __restrict__ W1, const float* __restrict__ b1,
    const float* __restrict__ W2, const float* __restrict__ b2,
    float* __restrict__ u, float* __restrict__ T, float* __restrict__ out)
{
    __shared__ SharedU sm;
    cg::grid_group grid = cg::this_grid();
    int tid = threadIdx.x;
    int blk = blockIdx.x;

    phase1(blk, tid, v, indices, W1, b1, u);
    __threadfence();
    grid.sync();
    phase2(blk, tid, sm, u, W1, T);
    __threadfence();
    grid.sync();
    phase3(blk, tid, sm, T, W1, W2, b2, out);
}

// ---------- fallback: same phases as 3 kernels ----------
__global__ __launch_bounds__(256) void k_prep(
    const float* __restrict__ v, const int* __restrict__ indices,
    const float* __restrict__ W1, const float* __restrict__ b1,
    float* __restrict__ u)
{
    phase1(blockIdx.x, threadIdx.x, v, indices, W1, b1, u);
}

__global__ __launch_bounds__(256) void k_table(
    const float* __restrict__ u, const float* __restrict__ W1,
    float* __restrict__ T)
{
    __shared__ SharedU sm;
    phase2(blockIdx.x, threadIdx.x, sm, u, W1, T);
}

__global__ __launch_bounds__(256) void k_eval(
    const float* __restrict__ T, const float* __restrict__ W1,
    const float* __restrict__ W2, const float* __restrict__ b2,
    float* __restrict__ out)
{
    __shared__ SharedU sm;
    phase3(blockIdx.x, threadIdx.x, sm, T, W1, W2, b2, out);
}

extern "C" void kernel_launch(void* const* d_in, const int* in_sizes, int n_in,
                              void* d_out, int out_size, void* d_ws, size_t ws_size,
                              hipStream_t stream) {
    const float* v       = (const float*)d_in[0];
    const int*   indices = (const int*)  d_in[1];
    const float* W1      = (const float*)d_in[2];
    const float* b1      = (const float*)d_in[3];
    const float* W2      = (const float*)d_in[4];
    const float* b2      = (const float*)d_in[5];
    float* out = (float*)d_out;
    float* u   = (float*)d_ws;                        // B*S*HID*4  = 128 KB
    float* T   = (float*)d_ws + (size_t)BB * S * HID; // B*HID*TN*4 =  64 KB

    void* args[] = { (void*)&v, (void*)&indices, (void*)&W1, (void*)&b1,
                     (void*)&W2, (void*)&b2, (void*)&u, (void*)&T, (void*)&out };
    hipError_t err = hipLaunchCooperativeKernel((const void*)nystrom_fused,
                                                dim3(GRID), dim3(256),
                                                args, 0, stream);
    if (err != hipSuccess) {
        // deterministic fallback: same phases as discrete kernels
        hipLaunchKernelGGL(k_prep,  dim3(BB * (S / 4)), dim3(256), 0, stream,
                           v, indices, W1, b1, u);
        hipLaunchKernelGGL(k_table, dim3(GRID),         dim3(256), 0, stream,
                           u, W1, T);
        hipLaunchKernelGGL(k_eval,  dim3(GRID),         dim3(256), 0, stream,
                           T, W1, W2, b2, out);
    }
}

// Round 7
// 25.960 us; speedup vs baseline: 4.3781x; 4.3781x over previous
//
#include <hip/hip_runtime.h>
#include <math.h>

#define BB 2
#define C_IN 32
#define HH 64
#define WW 64
#define J (HH*WW)        // 4096
#define HID 64
#define C_OUT 32
#define S 256
#define TN 128           // table knots per (b,h)
#define JT 32            // j's per eval block

// gelu(x) ~= x * sigmoid(A*x + B*x^3)  (tanh-form gelu, exp2 domain)
#define GELU_A 2.3022043f
#define GELU_B 0.10294306f

// ---------- kernel A: T[b,h,n] = sum_s gelu(c_n + u[b,s,h]) ----------
// u[b,:,h] recomputed in-block (34-dot per s) — no prep kernel needed.
__global__ __launch_bounds__(256) void k_table(
    const float* __restrict__ v, const int* __restrict__ indices,
    const float* __restrict__ W1, const float* __restrict__ b1,
    float* __restrict__ T)
{
    __shared__ float us[4 * 66];         // u[b,:,h] in 4 padded s-quarters
    int tid   = threadIdx.x;
    int blk   = blockIdx.x;              // 0..255
    int b     = blk >> 7;                // 0..1
    int q     = blk & 127;
    int h     = q >> 1;                  // 0..63
    int halfk = q & 1;                   // which 64 knots

    float w0 = W1[h], w1 = W1[HID + h];

    // --- recompute u[b,s,h] for s = tid ---
    {
        int s   = tid;
        int idx = indices[s];
        float sx = (float)(idx & (WW - 1)) * (1.0f / (WW - 1));
        float sy = (float)(idx >> 6)       * (1.0f / (HH - 1));
        float acc = b1[h] - sx * w0 - sy * w1;
        const float* vb = v + (size_t)b * C_IN * J + idx;
        #pragma unroll
        for (int c = 0; c < C_IN; ++c) {
            acc = __builtin_fmaf(vb[c * J], W1[(2 + c) * HID + h], acc);
        }
        us[(s >> 6) * 66 + (s & 63)] = acc;
    }
    __syncthreads();

    // --- knot sum: n = 64*halfk + tid>>2, 4 s-quarters in parallel ---
    float c0 = fminf(w0, 0.0f) + fminf(w1, 0.0f);
    float c1 = fmaxf(w0, 0.0f) + fmaxf(w1, 0.0f);
    float dc = fmaxf(c1 - c0, 1e-6f) * (1.0f / (TN - 1));
    int n  = halfk * 64 + (tid >> 2);
    int sq = tid & 3;
    float cn = c0 + (float)n * dc;

    const float* usp = &us[sq * 66];
    float acc = 0.0f;
    #pragma unroll 4
    for (int s = 0; s < 64; ++s) {
        float x = cn + usp[s];
        float p = __builtin_fmaf(-GELU_B, x * x, -GELU_A);
        float e = __builtin_amdgcn_exp2f(p * x);
        acc = __builtin_fmaf(x, __builtin_amdgcn_rcpf(e + 1.0f), acc);
    }
    acc += __shfl_xor(acc, 1);           // combine 4 s-quarters
    acc += __shfl_xor(acc, 2);
    if (sq == 0)
        T[((size_t)b * HID + h) * TN + n] = acc;
}

// ---------- kernel B: interp + W2 epilogue ----------
__global__ __launch_bounds__(256) void k_eval(
    const float* __restrict__ T, const float* __restrict__ W1,
    const float* __restrict__ W2, const float* __restrict__ b2,
    float* __restrict__ out)
{
    __shared__ float Tl[HID][TN + 4];    // row stride 132 floats, 16B-aligned
    __shared__ float G[JT][HID + 1];
    int tid = threadIdx.x;
    int blk = blockIdx.x;                // 0..255
    int b   = blk >> 7;
    int j0  = (blk & 127) * JT;

    // stage this batch's table (32 KB) into LDS, float4 loads
    const float4* Tb4 = (const float4*)(T + (size_t)b * HID * TN);
    #pragma unroll
    for (int k = tid; k < HID * TN / 4; k += 256) {   // 8 iters
        float4 vv = Tb4[k];
        int h = k >> 5;                  // 32 float4 per table row
        int n = (k & 31) * 4;
        *(float4*)&Tl[h][n] = vv;
    }
    __syncthreads();

    int jl = tid & 31;
    int j  = j0 + jl;
    float xj = (float)(j & (WW - 1)) * (1.0f / (WW - 1));
    float yj = (float)(j >> 6)       * (1.0f / (HH - 1));
    #pragma unroll
    for (int k = 0; k < 8; ++k) {
        int h = (tid >> 5) + k * 8;
        float w0 = W1[h], w1 = W1[HID + h];
        float c0 = fminf(w0, 0.0f) + fminf(w1, 0.0f);
        float c1 = fmaxf(w0, 0.0f) + fmaxf(w1, 0.0f);
        float inv = (float)(TN - 1) / fmaxf(c1 - c0, 1e-6f);
        float t  = (xj * w0 + yj * w1 - c0) * inv;
        int i = (int)t;
        i = max(0, min(TN - 2, i));
        float f = t - (float)i;
        float t0 = Tl[h][i], t1 = Tl[h][i + 1];
        G[jl][h] = __builtin_fmaf(f, t1 - t0, t0);
    }
    __syncthreads();

    // out[b,co,j0+jj]: lanes vary jj -> coalesced stores, conflict-free G reads
    int jj = tid & 31;
    int cb = tid >> 5;                   // 0..7
    #pragma unroll
    for (int qq = 0; qq < 4; ++qq) {
        int co = cb + 8 * qq;
        float sum = 0.0f;
        #pragma unroll
        for (int h = 0; h < HID; ++h)
            sum = __builtin_fmaf(G[jj][h], W2[h * C_OUT + co], sum);
        out[(size_t)b * C_OUT * J + (size_t)co * J + j0 + jj] = sum * (1.0f / S) + b2[co];
    }
}

extern "C" void kernel_launch(void* const* d_in, const int* in_sizes, int n_in,
                              void* d_out, int out_size, void* d_ws, size_t ws_size,
                              hipStream_t stream) {
    const float* v       = (const float*)d_in[0];
    const int*   indices = (const int*)  d_in[1];
    const float* W1      = (const float*)d_in[2];
    const float* b1      = (const float*)d_in[3];
    const float* W2      = (const float*)d_in[4];
    const float* b2      = (const float*)d_in[5];
    float* out = (float*)d_out;
    float* T   = (float*)d_ws;           // B*HID*TN*4 = 64 KB

    hipLaunchKernelGGL(k_table, dim3(256), dim3(256), 0, stream,
                       v, indices, W1, b1, T);
    hipLaunchKernelGGL(k_eval,  dim3(256), dim3(256), 0, stream,
                       T, W1, W2, b2, out);
}